// Round 1
// baseline (1589.397 us; speedup 1.0000x reference)
//
#include <hip/hip_runtime.h>
#include <math.h>

// Problem constants (from reference)
#define N_PTS 262144
#define BV 4
#define TV 4
#define PV 512
#define RV 256
#define CV 64
#define HH 512
#define WW 512

// Derived float constants — mirror the reference's float32 arithmetic:
//   y = c2*0.2f - 51.2f ; x = c3*0.2f - 51.2f
//   r_idx = r / 0.3f ; p_idx = (psi + pi_f) / float(2*pi/500)
__global__ __launch_bounds__(256) void pp_scatter_kernel(
    const int* __restrict__ coords,      // (N,4) int32: [b, z, y, x]
    const float* __restrict__ pview,     // (B,T,P,R,C) f32
    float* __restrict__ out)             // (B,C,H,W) f32, pre-filled with spatial_features
{
    const int wave = threadIdx.x >> 6;
    const int lane = threadIdx.x & 63;
    const int pt = (blockIdx.x << 2) + wave;
    if (pt >= N_PTS) return;

    // coords row is 16B-aligned int4; all 64 lanes load same address (broadcast)
    const int4 c = ((const int4*)coords)[pt];
    const int bi = c.x;   // b
    const int zz = c.y;   // z  -> W index of output, and T index of pview
    const int yi = c.z;   // y
    const int xi = c.w;   // x

    const float yf = (float)yi * 0.2f + (-51.2f);
    const float xf = (float)xi * 0.2f + (-51.2f);
    const float r  = sqrtf(xf * xf + yf * yf);
    const float PI_F = (float)M_PI;
    const float psi = (xf == 0.0f && yf >= 0.0f) ? (float)(M_PI / 2.0)
                                                 : atan2f(yf, xf);
    const float r_idx = r / 0.3f;                                  // (r - 0)/0.3
    const float p_idx = (psi + PI_F) / (float)(2.0 * M_PI / 500.0);

    int r0 = (int)floorf(r_idx);
    int p0 = (int)floorf(p_idx);
    const float fr = r_idx - (float)r0;
    const float fp = p_idx - (float)p0;
    int r1 = min(r0 + 1, RV - 1);
    int p1 = min(p0 + 1, PV - 1);
    // t frac is exactly 0 (t_idx is an integer) -> only jt=0 contributes, weight 1.

    const float w00 = (1.0f - fr) * (1.0f - fp);  // (r0, p0)
    const float w10 = fr * (1.0f - fp);           // (r1, p0)
    const float w01 = (1.0f - fr) * fp;           // (r0, p1)
    const float w11 = fr * fp;                    // (r1, p1)

    const size_t base = ((size_t)(bi * TV + zz)) * (size_t)(PV * RV * CV);
    const float g00 = pview[base + ((size_t)p0 * RV + r0) * CV + lane];
    const float g10 = pview[base + ((size_t)p0 * RV + r1) * CV + lane];
    const float g01 = pview[base + ((size_t)p1 * RV + r0) * CV + lane];
    const float g11 = pview[base + ((size_t)p1 * RV + r1) * CV + lane];

    const float feat = w00 * g00 + w10 * g10 + w01 * g01 + w11 * g11;

    // out[bi, lane, yi, zz]
    const size_t oidx = (((size_t)bi * CV + lane) * HH + yi) * WW + zz;
    atomicAdd(&out[oidx], feat);
}

extern "C" void kernel_launch(void* const* d_in, const int* in_sizes, int n_in,
                              void* d_out, int out_size, void* d_ws, size_t ws_size,
                              hipStream_t stream) {
    const int*   coords  = (const int*)d_in[0];    // (N,4) int32
    const float* pview   = (const float*)d_in[1];  // (4,4,512,256,64) f32
    const float* spatial = (const float*)d_in[2];  // (4,64,512,512) f32
    float* out = (float*)d_out;

    // 1) out = spatial_features (256 MB d2d copy, graph-capture safe)
    hipMemcpyAsync(out, spatial, (size_t)BV * CV * HH * WW * sizeof(float),
                   hipMemcpyDeviceToDevice, stream);

    // 2) scatter-add interpolated features; one wave per point, lane = channel
    dim3 grid(N_PTS / 4), block(256);
    pp_scatter_kernel<<<grid, block, 0, stream>>>(coords, pview, out);
}